// Round 1
// baseline (936.696 us; speedup 1.0000x reference)
//
#include <hip/hip_runtime.h>

#define C_DIM 16
#define H_DIM 64
#define HID_DIM 128
#define L_DIM 128
#define BB 8          // real batch rows per block (padded to 16 for MFMA)

typedef _Float16 f16;
typedef _Float16 f16x8 __attribute__((ext_vector_type(8)));
typedef float f32x4 __attribute__((ext_vector_type(4)));

__device__ __forceinline__ float fast_tanh(float x) {
    // tanh(x) = 1 - 2/(1+e^{2x}); e^{2x} = 2^{x*2*log2(e)}
    float e = __builtin_amdgcn_exp2f(x * 2.8853900817779268f);
    float r = __builtin_amdgcn_rcpf(e + 1.0f);
    return fmaf(-2.0f, r, 1.0f);   // large +x: e=inf -> r=0 -> 1; large -x: e=0 -> -1
}

__global__ void __launch_bounds__(512, 2)
cde_kernel(const float* __restrict__ coeffs,
           const float* __restrict__ W_init, const float* __restrict__ b_init,
           const float* __restrict__ W1, const float* __restrict__ b1,
           const float* __restrict__ W2, const float* __restrict__ b2,
           const float* __restrict__ W_out, const float* __restrict__ b_out,
           float* __restrict__ out)
{
    // LDS state. Row pads chosen so ds_read_b128 rows land 4 banks apart (2-way max = free).
    __shared__ __align__(16) float z32[BB][H_DIM];     // fp32 master state
    __shared__ __align__(16) float ksum[BB][H_DIM];    // RK4 accumulator
    __shared__ __align__(16) f16   z16[16][72];        // fp16 staged z (rows 8-15 = 0 pad)
    __shared__ __align__(16) f16   h16[16][136];       // fp16 hidden activations
    __shared__ __align__(16) float kl[2][16][68];      // k partials (c-halves from wave pairs)
    __shared__ __align__(16) float dxT[3][16][20];     // dX transposed [which][c][b]; b 8-15 = 0

    const int tid  = threadIdx.x;
    const int blk  = blockIdx.x;
    const int lane = tid & 63;
    const int w    = tid >> 6;        // wave 0..7
    const int q    = lane >> 4;       // quarter-wave 0..3
    const int lr   = lane & 15;
    const int hg   = w >> 1;          // hh-group (16 hh per group)
    const int c0   = (w & 1) * 8;     // this wave's c-range start

    // ---- one-time: weight fragments into registers ----
    // GEMM2 B-frag: tile (ct) = one c value x 16 hh values  ==> einsum's c-sum becomes
    // a register accumulation over ct, no cross-lane reduce.
    f16x8 w2f[8][4];
#pragma unroll
    for (int ct = 0; ct < 8; ++ct)
#pragma unroll
        for (int kc = 0; kc < 4; ++kc) {
            const float* src = W2 + (size_t)((hg * 16 + lr) * 16 + (c0 + ct)) * 128 + kc * 32 + q * 8;
            f16x8 v;
#pragma unroll
            for (int i = 0; i < 8; ++i) v[i] = (f16)src[i];
            w2f[ct][kc] = v;
        }
    f16x8 w1f[2];
#pragma unroll
    for (int kc = 0; kc < 2; ++kc) {
        const float* src = W1 + (size_t)(w * 16 + lr) * 64 + kc * 32 + q * 8;
        f16x8 v;
#pragma unroll
        for (int i = 0; i < 8; ++i) v[i] = (f16)src[i];
        w1f[kc] = v;
    }
    float b2r[8];
#pragma unroll
    for (int ct = 0; ct < 8; ++ct) b2r[ct] = b2[(hg * 16 + lr) * 16 + c0 + ct];
    const float b1r = b1[w * 16 + lr];

    // ---- init: z0 = X0 @ W_init^T + b_init (one thread per (b,hh); 512 = 8*64) ----
    {
        const int b = tid >> 6, hh = tid & 63;
        const float* x0 = coeffs + (size_t)(blk * BB + b) * (L_DIM - 1) * 64;
        float acc = b_init[hh];
#pragma unroll
        for (int c = 0; c < 16; ++c) acc = fmaf(x0[c], W_init[hh * 16 + c], acc);
        z32[b][hh] = acc;
        z16[b][hh] = (f16)acc;
    }
    for (int i = tid; i < 8 * 72; i += 512) z16[8 + i / 72][i % 72] = (f16)0.f;   // zero pad rows
    for (int i = tid; i < 3 * 16 * 8; i += 512) {                                  // zero pad batch cols
        int a = i / 128, c = (i / 8) % 16, b = 8 + (i & 7);
        dxT[a][c][b] = 0.f;
    }
    // spline derivs for t = 0 (coeffs layout per segment: [a(16), b(16), 2c(16), 3d(16)])
    if (tid < BB * C_DIM) {
        const int b = tid >> 4, c = tid & 15;
        const float* seg = coeffs + (size_t)(blk * BB + b) * (L_DIM - 1) * 64;
        float bv = seg[16 + c], cv = seg[32 + c], dv = seg[48 + c];
        dxT[0][c][b] = bv;                                   // fr = 0
        dxT[1][c][b] = fmaf(0.25f, dv, fmaf(0.5f, cv, bv));  // fr = 0.5
        dxT[2][c][b] = seg[64 + 16 + c];                     // next segment, fr = 0
    }
    __syncthreads();

    // ---- main time loop: 127 RK4 steps, 4 f-evals each ----
    for (int t = 0; t < L_DIM - 1; ++t) {
#pragma unroll
        for (int s = 0; s < 4; ++s) {
            // GEMM1: h = relu(z @ W1^T + b1)   (M=16, N=128, K=64)
            f16x8 za0 = *(const f16x8*)&z16[lr][q * 8];
            f16x8 za1 = *(const f16x8*)&z16[lr][32 + q * 8];
            f32x4 hacc = {0.f, 0.f, 0.f, 0.f};
            hacc = __builtin_amdgcn_mfma_f32_16x16x32_f16(za0, w1f[0], hacc, 0, 0, 0);
            hacc = __builtin_amdgcn_mfma_f32_16x16x32_f16(za1, w1f[1], hacc, 0, 0, 0);
#pragma unroll
            for (int r = 0; r < 4; ++r)
                h16[q * 4 + r][w * 16 + lr] = (f16)fmaxf(hacc[r] + b1r, 0.f);
            __syncthreads();

            // GEMM2 (M=16, N=1024, K=128) + tanh + dX contraction, all in-register
            f16x8 af0 = *(const f16x8*)&h16[lr][q * 8];
            f16x8 af1 = *(const f16x8*)&h16[lr][32 + q * 8];
            f16x8 af2 = *(const f16x8*)&h16[lr][64 + q * 8];
            f16x8 af3 = *(const f16x8*)&h16[lr][96 + q * 8];
            const int ds = (s == 0) ? 0 : ((s == 3) ? 2 : 1);
            float ka0 = 0.f, ka1 = 0.f, ka2 = 0.f, ka3 = 0.f;
#pragma unroll
            for (int ct = 0; ct < 8; ++ct) {
                f32x4 acc = {0.f, 0.f, 0.f, 0.f};
                acc = __builtin_amdgcn_mfma_f32_16x16x32_f16(af0, w2f[ct][0], acc, 0, 0, 0);
                acc = __builtin_amdgcn_mfma_f32_16x16x32_f16(af1, w2f[ct][1], acc, 0, 0, 0);
                acc = __builtin_amdgcn_mfma_f32_16x16x32_f16(af2, w2f[ct][2], acc, 0, 0, 0);
                acc = __builtin_amdgcn_mfma_f32_16x16x32_f16(af3, w2f[ct][3], acc, 0, 0, 0);
                f32x4 dv = *(const f32x4*)&dxT[ds][c0 + ct][q * 4];   // broadcast read
                ka0 = fmaf(fast_tanh(acc[0] + b2r[ct]), dv[0], ka0);
                ka1 = fmaf(fast_tanh(acc[1] + b2r[ct]), dv[1], ka1);
                ka2 = fmaf(fast_tanh(acc[2] + b2r[ct]), dv[2], ka2);
                ka3 = fmaf(fast_tanh(acc[3] + b2r[ct]), dv[3], ka3);
            }
            kl[w & 1][q * 4 + 0][hg * 16 + lr] = ka0;
            kl[w & 1][q * 4 + 1][hg * 16 + lr] = ka1;
            kl[w & 1][q * 4 + 2][hg * 16 + lr] = ka2;
            kl[w & 1][q * 4 + 3][hg * 16 + lr] = ka3;
            __syncthreads();

            // RK4 stage update (one thread per (b,hh))
            {
                const int b = tid >> 6, hh = tid & 63;
                float k  = kl[0][b][hh] + kl[1][b][hh];
                float zc = z32[b][hh];
                if (s == 0)      { ksum[b][hh] = k;          z16[b][hh] = (f16)fmaf(0.5f, k, zc); }
                else if (s == 1) { ksum[b][hh] += 2.f * k;   z16[b][hh] = (f16)fmaf(0.5f, k, zc); }
                else if (s == 2) { ksum[b][hh] += 2.f * k;   z16[b][hh] = (f16)(zc + k); }
                else {
                    float zn = fmaf(ksum[b][hh] + k, 1.f / 6.f, zc);
                    z32[b][hh] = zn;
                    z16[b][hh] = (f16)zn;
                }
            }
            // prefetch next step's spline derivs (dx for step t fully consumed above)
            if (s == 3 && t + 1 < L_DIM - 1 && tid < BB * C_DIM) {
                const int b = tid >> 4, c = tid & 15;
                const float* seg = coeffs + ((size_t)(blk * BB + b) * (L_DIM - 1) + (t + 1)) * 64;
                float bv = seg[16 + c], cv = seg[32 + c], dv2 = seg[48 + c];
                dxT[0][c][b] = bv;
                dxT[1][c][b] = fmaf(0.25f, dv2, fmaf(0.5f, cv, bv));
                dxT[2][c][b] = (t + 1 < L_DIM - 2) ? seg[64 + 16 + c]       // next seg, fr=0
                                                   : (bv + cv + dv2);       // last seg, fr=1
            }
            __syncthreads();
        }
    }

    // ---- epilogue: out = zT @ W_out^T + b_out ----
    if (tid < 64) {
        const int b = lane >> 3, j0 = lane & 7;
        float p = 0.f;
#pragma unroll
        for (int m = 0; m < 8; ++m) p += z32[b][j0 + 8 * m] * W_out[j0 + 8 * m];
        p += __shfl_xor(p, 1, 64);
        p += __shfl_xor(p, 2, 64);
        p += __shfl_xor(p, 4, 64);
        if (j0 == 0) out[blk * BB + b] = p + b_out[0];
    }
}

extern "C" void kernel_launch(void* const* d_in, const int* in_sizes, int n_in,
                              void* d_out, int out_size, void* d_ws, size_t ws_size,
                              hipStream_t stream) {
    const float* coeffs = (const float*)d_in[0];
    const float* W_init = (const float*)d_in[1];
    const float* b_init = (const float*)d_in[2];
    const float* W1     = (const float*)d_in[3];
    const float* b1     = (const float*)d_in[4];
    const float* W2     = (const float*)d_in[5];
    const float* b2     = (const float*)d_in[6];
    const float* W_out  = (const float*)d_in[7];
    const float* b_out  = (const float*)d_in[8];
    cde_kernel<<<256, 512, 0, stream>>>(coeffs, W_init, b_init, W1, b1, W2, b2,
                                        W_out, b_out, (float*)d_out);
}